// Round 11
// baseline (51.725 us; speedup 1.0000x reference)
//
#include <hip/hip_runtime.h>
#include <cstdint>
#include <cstddef>

#define NN   32768
#define BATCH 16
#define LL   2048          // NN / BATCH
#define KNN  9
#define NE   (NN * KNN)    // 294912
#define PLM  5             // per-lane list size
#define MTOP 12            // global candidates extracted before exact resort
#define RPW  4             // rows per wave
#define TPB  1024          // threads per block (16 waves)
#define ROWS_PB ((TPB / 64) * RPW)   // 64 rows per block -> grid = 512

typedef float vf2 __attribute__((ext_vector_type(2)));

// ---------------- helpers ----------------

// Reference-exact squared distance (non-fused, fixed association) — used only
// in the exact resort and feature phases.
__device__ __forceinline__ float ref_d2(float ax, float ay, float az,
                                        float bx, float by, float bz) {
    float dx = __fsub_rn(ax, bx);
    float dy = __fsub_rn(ay, by);
    float dz = __fsub_rn(az, bz);
    return __fadd_rn(__fadd_rn(__fmul_rn(dx, dx), __fmul_rn(dy, dy)),
                     __fmul_rn(dz, dz));
}

__device__ __forceinline__ float ref_dist(float ax, float ay, float az,
                                          float bx, float by, float bz) {
    return sqrtf(__fadd_rn(ref_d2(ax, ay, az, bx, by, bz), 1e-6f));
}

// v_med3_u32: median of 3 (gfx9-lineage VOP3, present on CDNA).
__device__ __forceinline__ unsigned umed3(unsigned a, unsigned b, unsigned c) {
    unsigned r;
    asm("v_med3_u32 %0, %1, %2, %3" : "=v"(r) : "v"(a), "v"(b), "v"(c));
    return r;
}

// sorted-insert of cur into 5-slot ascending list: r0=min, rk=med3(a[k-1],a[k],cur)
__device__ __forceinline__ void insert5(unsigned* l, unsigned cur) {
    unsigned n0 = min(l[0], cur);
    unsigned n1 = umed3(l[0], l[1], cur);
    unsigned n2 = umed3(l[1], l[2], cur);
    unsigned n3 = umed3(l[2], l[3], cur);
    unsigned n4 = umed3(l[3], l[4], cur);
    l[0] = n0; l[1] = n1; l[2] = n2; l[3] = n3; l[4] = n4;
}

// 16-lane min butterfly via row_ror (all lanes valid, bound_ctrl=true -> fusable).
__device__ __forceinline__ unsigned dpp_min16_ror(unsigned x) {
    unsigned t;
    t = (unsigned)__builtin_amdgcn_update_dpp(0, (int)x, 0x121, 0xf, 0xf, true); // ror:1
    x = min(x, t);
    t = (unsigned)__builtin_amdgcn_update_dpp(0, (int)x, 0x122, 0xf, 0xf, true); // ror:2
    x = min(x, t);
    t = (unsigned)__builtin_amdgcn_update_dpp(0, (int)x, 0x124, 0xf, 0xf, true); // ror:4
    x = min(x, t);
    t = (unsigned)__builtin_amdgcn_update_dpp(0, (int)x, 0x128, 0xf, 0xf, true); // ror:8
    x = min(x, t);
    return x;   // every lane holds its 16-group min
}

__device__ __forceinline__ unsigned gather_min(unsigned a) {
    unsigned m0 = min((unsigned)__builtin_amdgcn_readlane((int)a, 15),
                      (unsigned)__builtin_amdgcn_readlane((int)a, 31));
    unsigned m1 = min((unsigned)__builtin_amdgcn_readlane((int)a, 47),
                      (unsigned)__builtin_amdgcn_readlane((int)a, 63));
    return min(m0, m1);   // uniform (SALU)
}

// ---------------- single fused kernel ----------------
//  A) stage CA coords SoA (sx,sy,sz,|p|^2), row atoms, packed seg/isg codes
//  B) scan: 4 candidates/lane/iter via packed v_pk_fma_f32 d2 pairs;
//     per-lane top-5 of truncated-(d2+1)|idx keys, med3 insert
//  C) extraction: 12 rounds, 4 row-chains interleaved (ror-DPP + readlane)
//  D) rank assignment: tie-free fast path or exact (sqrt,j) resort
//  E) edge RBF features: float4 stores
//  F) node RBF features: single float4 pass
__global__ __launch_bounds__(TPB, 8) void fused_kernel(
    const float* __restrict__ X, const int* __restrict__ seg,
    const int* __restrict__ isg_raw,
    float* __restrict__ node_out, float* __restrict__ edge_out,
    float* __restrict__ out_row, float* __restrict__ out_col,
    float* __restrict__ out_ctx, float* __restrict__ out_inter)
{
    __shared__ float sx[LL], sy[LL], sz[LL], sn[LL];   // 32 KB SoA
    __shared__ float rowatoms[ROWS_PB * 12];           // 3 KB
    __shared__ unsigned char code[LL];                 // 2 KB: seg | (isg<<2)
    __shared__ int colsL[TPB / 64][RPW][KNN];          // finalist local idx
    __shared__ int flag;

    int tid  = threadIdx.x;
    int row0 = blockIdx.x * ROWS_PB;
    int base = row0 & ~(LL - 1);

    // --- A: is_global layout detection (bytes vs int32), staging ---
    if (tid == 0) flag = 0;
    __syncthreads();
    if (tid < 512) {
        // 512 ints cover the batch's byte-layout region; packed 0/1 bytes give
        // a word>1 with P = 1-8^-512 (certain); int32 bools never do.
        unsigned v = (unsigned)isg_raw[(base >> 2) + tid];
        if (v > 1u) atomicOr(&flag, 1);
    }
    if (tid < ROWS_PB * 12)
        rowatoms[tid] = X[(size_t)row0 * 12 + tid];
    __syncthreads();
    bool as_bytes = (flag != 0);
    for (int t = tid; t < LL; t += TPB) {
        const float* p = X + (size_t)(base + t) * 12 + 3;   // atom 1 (CA)
        float x = p[0], y = p[1], z = p[2];
        sx[t] = x; sy[t] = y; sz[t] = z;
        sn[t] = fmaf(x, x, fmaf(y, y, z * z));
        int ig = as_bytes ? (int)((const unsigned char*)isg_raw)[base + t]
                          : isg_raw[base + t];
        code[t] = (unsigned char)((seg[base + t] & 3) | (ig ? 4 : 0));
    }
    __syncthreads();

    int lane = tid & 63;
    int warp = tid >> 6;
    int gi0  = row0 + warp * RPW;
    int i0   = gi0 - base;

    // hoisted per-row scan constants: (-2x, -2y, -2z, |p|^2 + 1)
    float qx2[RPW], qy2[RPW], qz2[RPW], qn1[RPW];
#pragma unroll
    for (int r = 0; r < RPW; ++r) {
        qx2[r] = -2.0f * sx[i0 + r];
        qy2[r] = -2.0f * sy[i0 + r];
        qz2[r] = -2.0f * sz[i0 + r];
        qn1[r] = sn[i0 + r] + 1.0f;
    }

    // --- B: scan (packed pairs; per-candidate math bit-identical to R10) ---
    unsigned lst[RPW][PLM];
#pragma unroll
    for (int r = 0; r < RPW; ++r)
#pragma unroll
        for (int k = 0; k < PLM; ++k) lst[r][k] = 0xFFFFFFFFu;

#pragma unroll 8
    for (int s = 0; s < LL / 256; ++s) {
        int j = (s << 8) | (lane << 2);
        float4 cx = *(const float4*)&sx[j];
        float4 cy = *(const float4*)&sy[j];
        float4 cz = *(const float4*)&sz[j];
        float4 cn = *(const float4*)&sn[j];
        vf2 cx01 = {cx.x, cx.y}, cx23 = {cx.z, cx.w};
        vf2 cy01 = {cy.x, cy.y}, cy23 = {cy.z, cy.w};
        vf2 cz01 = {cz.x, cz.y}, cz23 = {cz.z, cz.w};
        vf2 cn01 = {cn.x, cn.y}, cn23 = {cn.z, cn.w};
#pragma unroll
        for (int r = 0; r < RPW; ++r) {
            vf2 qx = {qx2[r], qx2[r]};
            vf2 qy = {qy2[r], qy2[r]};
            vf2 qz = {qz2[r], qz2[r]};
            vf2 qn = {qn1[r], qn1[r]};
            vf2 d01 = __builtin_elementwise_fma(qx, cx01,
                      __builtin_elementwise_fma(qy, cy01,
                      __builtin_elementwise_fma(qz, cz01, qn + cn01)));
            vf2 d23 = __builtin_elementwise_fma(qx, cx23,
                      __builtin_elementwise_fma(qy, cy23,
                      __builtin_elementwise_fma(qz, cz23, qn + cn23)));
            unsigned c0 = (__float_as_uint(d01.x) & 0xFFFFF800u) | (unsigned)(j + 0);
            unsigned c1 = (__float_as_uint(d01.y) & 0xFFFFF800u) | (unsigned)(j + 1);
            unsigned c2 = (__float_as_uint(d23.x) & 0xFFFFF800u) | (unsigned)(j + 2);
            unsigned c3 = (__float_as_uint(d23.y) & 0xFFFFF800u) | (unsigned)(j + 3);
            insert5(lst[r], c0);
            insert5(lst[r], c1);
            insert5(lst[r], c2);
            insert5(lst[r], c3);
        }
    }

    // --- C: extraction (4 row-chains interleaved per round) ---
    unsigned mine[RPW];
#pragma unroll
    for (int r = 0; r < RPW; ++r) mine[r] = 0xFFFFFFFFu;

#pragma unroll
    for (int t = 0; t < MTOP; ++t) {
        unsigned a[RPW], m[RPW];
#pragma unroll
        for (int r = 0; r < RPW; ++r) a[r] = dpp_min16_ror(lst[r][0]);
#pragma unroll
        for (int r = 0; r < RPW; ++r) m[r] = gather_min(a[r]);
#pragma unroll
        for (int r = 0; r < RPW; ++r) {
            bool rem = (lst[r][0] == m[r]);   // keys unique -> at most one lane
#pragma unroll
            for (int k = 0; k < PLM - 1; ++k) lst[r][k] = rem ? lst[r][k + 1] : lst[r][k];
            lst[r][PLM - 1] = rem ? 0xFFFFFFFFu : lst[r][PLM - 1];
            mine[r] = (lane == t) ? m[r] : mine[r];
        }
    }

    // --- D: rank assignment + graph outputs, per row ---
#pragma unroll
    for (int r = 0; r < RPW; ++r) {
        int gi = gi0 + r;
        int jf = (int)(mine[r] & (LL - 1));

        // tie check: exact order can differ from trunc order only if
        // consecutive finalists share the same truncated-d2' bits.
        unsigned nbr = (unsigned)__builtin_amdgcn_update_dpp(
            (int)0xFFFFFFFF, (int)mine[r], 0x101 /*row_shl:1*/, 0xf, 0xf, false);
        bool tie = (lane < 11) && ((mine[r] ^ nbr) < 2048u);

        int rank;
        if (!__any(tie)) {
            rank = lane;                      // trunc order == exact order
        } else {
            float qxr = sx[i0 + r], qyr = sy[i0 + r], qzr = sz[i0 + r];
            float cjx = sx[jf], cjy = sy[jf], cjz = sz[jf];
            float D = sqrtf(__fadd_rn(ref_d2(qxr, qyr, qzr, cjx, cjy, cjz), 1e-6f));
            rank = 0;
#pragma unroll
            for (int t = 0; t < MTOP; ++t) {
                float Dt = __int_as_float(__builtin_amdgcn_readlane(__float_as_int(D), t));
                int   jt = __builtin_amdgcn_readlane(jf, t);
                bool lt = (Dt < D) || (Dt == D && jt < jf);
                rank += lt ? 1 : 0;
            }
        }

        if (lane < MTOP && rank < KNN) {
            int cg = base + jf;
            int e  = gi * KNN + rank;
            out_row[e] = (float)gi;
            out_col[e] = (float)cg;
            int cr = code[gi - base], cc = code[jf];
            int ng = ((cr | cc) & 4) ? 0 : 1;
            int sr = cr & 3, sc = cc & 3;
            out_ctx[e]   = (sr == sc && ng) ? 1.0f : 0.0f;
            out_inter[e] = (sr != sc && ng) ? 1.0f : 0.0f;
            colsL[warp][r][rank] = jf;
        }
    }

    // --- E: edge RBF features, float4 stores ---
    {
        int g = lane & 15, sE = lane >> 4;
        int atomE = g >> 2;
        float zk[4];
        float tbE = (float)((g & 3) * 4);
#pragma unroll
        for (int k = 0; k < 4; ++k)
            zk[k] = -(tbE + (float)k) * (20.0f / 15.0f) * 0.8f;  // -mu*0.8
        int rA = warp * RPW;
        if (sE < 3) {
#pragma unroll
            for (int p = 0; p < 3 * RPW; ++p) {
                int r = p / 3;                    // static after unroll
                int q = (p % 3) * 3 + sE;         // 0..8
                int jf = colsL[warp][r][q];
                float cjx = sx[jf], cjy = sy[jf], cjz = sz[jf];
                const float* ra = &rowatoms[(rA + r) * 12 + atomE * 3];
                float d = ref_dist(ra[0], ra[1], ra[2], cjx, cjy, cjz);
                float4 v;
                float z0 = fmaf(d, 0.8f, zk[0]); v.x = __expf(-z0 * z0);
                float z1 = fmaf(d, 0.8f, zk[1]); v.y = __expf(-z1 * z1);
                float z2 = fmaf(d, 0.8f, zk[2]); v.z = __expf(-z2 * z2);
                float z3 = fmaf(d, 0.8f, zk[3]); v.w = __expf(-z3 * z3);
                *(float4*)(edge_out + ((size_t)(gi0 + r) * KNN + q) * 64 + g * 4) = v;
            }
        }
    }

    // --- F: node RBF features, single float4 pass ---
    if (lane < 48) {
        int rn = lane / 12;
        int c4 = lane - rn * 12;
        int aN = c4 >> 2;
        int asrc = (aN == 0) ? 0 : aN + 1;        // atoms 0, 2, 3 vs CA
        float tbN = (float)((c4 & 3) * 4);
        float zn[4];
#pragma unroll
        for (int k = 0; k < 4; ++k)
            zn[k] = -(tbN + (float)k) * (20.0f / 15.0f) * 0.8f;
        const float* ra = &rowatoms[(warp * RPW + rn) * 12 + asrc * 3];
        float cax = sx[i0 + rn], cay = sy[i0 + rn], caz = sz[i0 + rn];
        float d = ref_dist(ra[0], ra[1], ra[2], cax, cay, caz);
        float4 v;
        float z0 = fmaf(d, 0.8f, zn[0]); v.x = __expf(-z0 * z0);
        float z1 = fmaf(d, 0.8f, zn[1]); v.y = __expf(-z1 * z1);
        float z2 = fmaf(d, 0.8f, zn[2]); v.z = __expf(-z2 * z2);
        float z3 = fmaf(d, 0.8f, zn[3]); v.w = __expf(-z3 * z3);
        *(float4*)(node_out + (size_t)(gi0 + rn) * 48 + c4 * 4) = v;
    }
}

// ---------------- launcher ----------------
extern "C" void kernel_launch(void* const* d_in, const int* in_sizes, int n_in,
                              void* d_out, int out_size, void* d_ws, size_t ws_size,
                              hipStream_t stream) {
    const float* X       = (const float*)d_in[0];
    const int*   seg     = (const int*)d_in[1];
    const int*   isg_raw = (const int*)d_in[2];

    float* out = (float*)d_out;
    float* node_out  = out;                                   // [NN*48]
    float* edge_out  = out + (size_t)NN * 48;                 // [NE*64]
    float* row_out   = edge_out + (size_t)NE * 64;            // [NE]
    float* col_out   = row_out + NE;                          // [NE]
    float* ctx_out   = col_out + NE;                          // [NE]
    float* inter_out = ctx_out + NE;                          // [NE]

    hipLaunchKernelGGL(fused_kernel, dim3(NN / ROWS_PB), dim3(TPB), 0, stream,
                       X, seg, isg_raw,
                       node_out, edge_out, row_out, col_out, ctx_out, inter_out);
}

// Round 14
// 48.933 us; speedup vs baseline: 1.0571x; 1.0571x over previous
//
#include <hip/hip_runtime.h>
#include <cstdint>
#include <cstddef>

#define NN   32768
#define BATCH 16
#define LL   2048          // NN / BATCH
#define KNN  9
#define NE   (NN * KNN)    // 294912
#define PLM  5             // per-lane list size
#define MTOP 12            // global candidates extracted before exact resort
#define RPW  4             // rows per wave
#define TPB  1024          // threads per block (16 waves)
#define ROWS_PB ((TPB / 64) * RPW)   // 64 rows per block -> grid = 512

// ---------------- helpers ----------------

// Reference-exact squared distance (non-fused, fixed association) — used only
// in the exact resort and feature phases.
__device__ __forceinline__ float ref_d2(float ax, float ay, float az,
                                        float bx, float by, float bz) {
    float dx = __fsub_rn(ax, bx);
    float dy = __fsub_rn(ay, by);
    float dz = __fsub_rn(az, bz);
    return __fadd_rn(__fadd_rn(__fmul_rn(dx, dx), __fmul_rn(dy, dy)),
                     __fmul_rn(dz, dz));
}

__device__ __forceinline__ float ref_dist(float ax, float ay, float az,
                                          float bx, float by, float bz) {
    return sqrtf(__fadd_rn(ref_d2(ax, ay, az, bx, by, bz), 1e-6f));
}

// v_med3_u32: median of 3 (gfx9-lineage VOP3, present on CDNA).
__device__ __forceinline__ unsigned umed3(unsigned a, unsigned b, unsigned c) {
    unsigned r;
    asm("v_med3_u32 %0, %1, %2, %3" : "=v"(r) : "v"(a), "v"(b), "v"(c));
    return r;
}

// 16-lane min butterfly via row_ror (all lanes valid, bound_ctrl=true).
__device__ __forceinline__ unsigned dpp_min16_ror(unsigned x) {
    unsigned t;
    t = (unsigned)__builtin_amdgcn_update_dpp(0, (int)x, 0x121, 0xf, 0xf, true); // ror:1
    x = min(x, t);
    t = (unsigned)__builtin_amdgcn_update_dpp(0, (int)x, 0x122, 0xf, 0xf, true); // ror:2
    x = min(x, t);
    t = (unsigned)__builtin_amdgcn_update_dpp(0, (int)x, 0x124, 0xf, 0xf, true); // ror:4
    x = min(x, t);
    t = (unsigned)__builtin_amdgcn_update_dpp(0, (int)x, 0x128, 0xf, 0xf, true); // ror:8
    x = min(x, t);
    return x;   // every lane holds its 16-group min
}

__device__ __forceinline__ unsigned gather_min(unsigned a) {
    unsigned m0 = min((unsigned)__builtin_amdgcn_readlane((int)a, 15),
                      (unsigned)__builtin_amdgcn_readlane((int)a, 31));
    unsigned m1 = min((unsigned)__builtin_amdgcn_readlane((int)a, 47),
                      (unsigned)__builtin_amdgcn_readlane((int)a, 63));
    return min(m0, m1);   // uniform
}

// ---------------- single fused kernel ----------------
//  A) stage CA coords (float4 w/ |p|^2), row atoms, packed seg/isg codes
//  B) scan: per-lane top-5 of truncated-(d2+1)|idx keys, med3 insert
//  C) extraction: 12 rounds, 4 row-chains interleaved (ror-DPP + readlane)
//  D) rank assignment: tie-free fast path or exact (sqrt,j) resort
//  E) edge RBF features: float4 stores
//  F) node RBF features: single float4 pass
__global__ __launch_bounds__(TPB, 8) void fused_kernel(
    const float* __restrict__ X, const int* __restrict__ seg,
    const int* __restrict__ isg_raw,
    float* __restrict__ node_out, float* __restrict__ edge_out,
    float* __restrict__ out_row, float* __restrict__ out_col,
    float* __restrict__ out_ctx, float* __restrict__ out_inter)
{
    __shared__ float4 crd[LL];                 // 32 KB: x, y, z, |p|^2
    __shared__ float rowatoms[ROWS_PB * 12];   // 3 KB
    __shared__ unsigned char code[LL];         // 2 KB: seg | (isg<<2)
    __shared__ int colsL[TPB / 64][RPW][KNN];  // finalist local idx per rank
    __shared__ int flag;

    int tid  = threadIdx.x;
    int row0 = blockIdx.x * ROWS_PB;
    int base = row0 & ~(LL - 1);

    // --- A: is_global layout detection (bytes vs int32), staging ---
    if (tid == 0) flag = 0;
    __syncthreads();
    if (tid < 512) {
        // 512 ints cover the batch's byte-layout region; packed 0/1 bytes give
        // a word>1 with P = 1-8^-512 (certain); int32 bools never do.
        unsigned v = (unsigned)isg_raw[(base >> 2) + tid];
        if (v > 1u) atomicOr(&flag, 1);
    }
    if (tid < ROWS_PB * 12)
        rowatoms[tid] = X[(size_t)row0 * 12 + tid];
    __syncthreads();
    bool as_bytes = (flag != 0);
    for (int t = tid; t < LL; t += TPB) {
        const float* p = X + (size_t)(base + t) * 12 + 3;   // atom 1 (CA)
        float x = p[0], y = p[1], z = p[2];
        crd[t] = make_float4(x, y, z, fmaf(x, x, fmaf(y, y, z * z)));
        int ig = as_bytes ? (int)((const unsigned char*)isg_raw)[base + t]
                          : isg_raw[base + t];
        code[t] = (unsigned char)((seg[base + t] & 3) | (ig ? 4 : 0));
    }
    __syncthreads();

    int lane = tid & 63;
    int warp = tid >> 6;
    int gi0  = row0 + warp * RPW;
    int i0   = gi0 - base;

    // hoisted per-row scan constants: (-2x, -2y, -2z, |p|^2 + 1)
    // (+1 bias keeps d2' = d2+1 >= ~1 > 0, so no clamp needed; monotone in d2)
    float qx2[RPW], qy2[RPW], qz2[RPW], qn1[RPW];
#pragma unroll
    for (int r = 0; r < RPW; ++r) {
        float4 ci = crd[i0 + r];
        qx2[r] = -2.0f * ci.x; qy2[r] = -2.0f * ci.y; qz2[r] = -2.0f * ci.z;
        qn1[r] = ci.w + 1.0f;
    }

    // --- B: scan ---
    unsigned lst[RPW][PLM];
#pragma unroll
    for (int r = 0; r < RPW; ++r)
#pragma unroll
        for (int k = 0; k < PLM; ++k) lst[r][k] = 0xFFFFFFFFu;

#pragma unroll 8
    for (int s = 0; s < LL / 64; ++s) {
        int j = (s << 6) | lane;
        float4 c = crd[j];
#pragma unroll
        for (int r = 0; r < RPW; ++r) {
            float d2 = fmaf(qx2[r], c.x,
                       fmaf(qy2[r], c.y,
                       fmaf(qz2[r], c.z, qn1[r] + c.w)));
            unsigned cur = (__float_as_uint(d2) & 0xFFFFF800u) | (unsigned)j;
            // sorted-insert via med3: r0 = min, rk = med3(a[k-1], a[k], cur)
            unsigned n0 = min(lst[r][0], cur);
            unsigned n1 = umed3(lst[r][0], lst[r][1], cur);
            unsigned n2 = umed3(lst[r][1], lst[r][2], cur);
            unsigned n3 = umed3(lst[r][2], lst[r][3], cur);
            unsigned n4 = umed3(lst[r][3], lst[r][4], cur);
            lst[r][0] = n0; lst[r][1] = n1; lst[r][2] = n2;
            lst[r][3] = n3; lst[r][4] = n4;
        }
    }

    // --- C: extraction (4 row-chains interleaved per round) ---
    unsigned mine[RPW];
#pragma unroll
    for (int r = 0; r < RPW; ++r) mine[r] = 0xFFFFFFFFu;

#pragma unroll
    for (int t = 0; t < MTOP; ++t) {
        unsigned a[RPW], m[RPW];
#pragma unroll
        for (int r = 0; r < RPW; ++r) a[r] = dpp_min16_ror(lst[r][0]);
#pragma unroll
        for (int r = 0; r < RPW; ++r) m[r] = gather_min(a[r]);
#pragma unroll
        for (int r = 0; r < RPW; ++r) {
            bool rem = (lst[r][0] == m[r]);   // keys unique -> at most one lane
#pragma unroll
            for (int k = 0; k < PLM - 1; ++k) lst[r][k] = rem ? lst[r][k + 1] : lst[r][k];
            lst[r][PLM - 1] = rem ? 0xFFFFFFFFu : lst[r][PLM - 1];
            mine[r] = (lane == t) ? m[r] : mine[r];
        }
    }

    // --- D: rank assignment + graph outputs, per row ---
#pragma unroll
    for (int r = 0; r < RPW; ++r) {
        int gi = gi0 + r;
        int jf = (int)(mine[r] & (LL - 1));

        // tie check: exact order can differ from trunc order only if
        // consecutive finalists share the same truncated-d2' bits.
        unsigned nbr = (unsigned)__builtin_amdgcn_update_dpp(
            (int)0xFFFFFFFF, (int)mine[r], 0x101 /*row_shl:1*/, 0xf, 0xf, false);
        bool tie = (lane < 11) && ((mine[r] ^ nbr) < 2048u);

        int rank;
        if (!__any(tie)) {
            rank = lane;                      // trunc order == exact order
        } else {
            float4 ci = crd[i0 + r];
            float4 cj = crd[jf];
            float D = sqrtf(__fadd_rn(ref_d2(ci.x, ci.y, ci.z, cj.x, cj.y, cj.z), 1e-6f));
            rank = 0;
#pragma unroll
            for (int t = 0; t < MTOP; ++t) {
                float Dt = __int_as_float(__builtin_amdgcn_readlane(__float_as_int(D), t));
                int   jt = __builtin_amdgcn_readlane(jf, t);
                bool lt = (Dt < D) || (Dt == D && jt < jf);
                rank += lt ? 1 : 0;
            }
        }

        if (lane < MTOP && rank < KNN) {
            int cg = base + jf;
            int e  = gi * KNN + rank;
            out_row[e] = (float)gi;
            out_col[e] = (float)cg;
            int cr = code[gi - base], cc = code[jf];
            int ng = ((cr | cc) & 4) ? 0 : 1;
            int sr = cr & 3, sc = cc & 3;
            out_ctx[e]   = (sr == sc && ng) ? 1.0f : 0.0f;
            out_inter[e] = (sr != sc && ng) ? 1.0f : 0.0f;
            colsL[warp][r][rank] = jf;
        }
    }

    // --- E: edge RBF features, float4 stores ---
    {
        int g = lane & 15, sE = lane >> 4;
        int atomE = g >> 2;
        float zk[4];
        float tbE = (float)((g & 3) * 4);
#pragma unroll
        for (int k = 0; k < 4; ++k)
            zk[k] = -(tbE + (float)k) * (20.0f / 15.0f) * 0.8f;  // -mu*0.8
        int rA = warp * RPW;
        if (sE < 3) {
#pragma unroll
            for (int p = 0; p < 3 * RPW; ++p) {
                int r = p / 3;                    // static after unroll
                int q = (p % 3) * 3 + sE;         // 0..8
                int jf = colsL[warp][r][q];
                float4 cj = crd[jf];
                const float* ra = &rowatoms[(rA + r) * 12 + atomE * 3];
                float d = ref_dist(ra[0], ra[1], ra[2], cj.x, cj.y, cj.z);
                float4 v;
                float z0 = fmaf(d, 0.8f, zk[0]); v.x = __expf(-z0 * z0);
                float z1 = fmaf(d, 0.8f, zk[1]); v.y = __expf(-z1 * z1);
                float z2 = fmaf(d, 0.8f, zk[2]); v.z = __expf(-z2 * z2);
                float z3 = fmaf(d, 0.8f, zk[3]); v.w = __expf(-z3 * z3);
                *(float4*)(edge_out + ((size_t)(gi0 + r) * KNN + q) * 64 + g * 4) = v;
            }
        }
    }

    // --- F: node RBF features, single float4 pass ---
    if (lane < 48) {
        int rn = lane / 12;
        int c4 = lane - rn * 12;
        int aN = c4 >> 2;
        int asrc = (aN == 0) ? 0 : aN + 1;        // atoms 0, 2, 3 vs CA
        float tbN = (float)((c4 & 3) * 4);
        float zn[4];
#pragma unroll
        for (int k = 0; k < 4; ++k)
            zn[k] = -(tbN + (float)k) * (20.0f / 15.0f) * 0.8f;
        const float* ra = &rowatoms[(warp * RPW + rn) * 12 + asrc * 3];
        float4 ca = crd[i0 + rn];
        float d = ref_dist(ra[0], ra[1], ra[2], ca.x, ca.y, ca.z);
        float4 v;
        float z0 = fmaf(d, 0.8f, zn[0]); v.x = __expf(-z0 * z0);
        float z1 = fmaf(d, 0.8f, zn[1]); v.y = __expf(-z1 * z1);
        float z2 = fmaf(d, 0.8f, zn[2]); v.z = __expf(-z2 * z2);
        float z3 = fmaf(d, 0.8f, zn[3]); v.w = __expf(-z3 * z3);
        *(float4*)(node_out + (size_t)(gi0 + rn) * 48 + c4 * 4) = v;
    }
}

// ---------------- launcher ----------------
extern "C" void kernel_launch(void* const* d_in, const int* in_sizes, int n_in,
                              void* d_out, int out_size, void* d_ws, size_t ws_size,
                              hipStream_t stream) {
    const float* X       = (const float*)d_in[0];
    const int*   seg     = (const int*)d_in[1];
    const int*   isg_raw = (const int*)d_in[2];

    float* out = (float*)d_out;
    float* node_out  = out;                                   // [NN*48]
    float* edge_out  = out + (size_t)NN * 48;                 // [NE*64]
    float* row_out   = edge_out + (size_t)NE * 64;            // [NE]
    float* col_out   = row_out + NE;                          // [NE]
    float* ctx_out   = col_out + NE;                          // [NE]
    float* inter_out = ctx_out + NE;                          // [NE]

    hipLaunchKernelGGL(fused_kernel, dim3(NN / ROWS_PB), dim3(TPB), 0, stream,
                       X, seg, isg_raw,
                       node_out, edge_out, row_out, col_out, ctx_out, inter_out);
}